// Round 6
// baseline (86.451 us; speedup 1.0000x reference)
//
#include <hip/hip_runtime.h>
#include <hip/hip_bf16.h>
#include <math.h>

#define BGR 128   // graphs
#define NND 512   // nodes per graph
#define DFD 128   // feature dim
#define KKP 256   // kept nodes per graph

typedef unsigned int uint;
typedef unsigned long long ull;
typedef float  fvec4 __attribute__((ext_vector_type(4)));
typedef float  fvec2 __attribute__((ext_vector_type(2)));
typedef uint   uvec4 __attribute__((ext_vector_type(4)));

__device__ inline fvec4 ntload4(const float* p) {
    return __builtin_nontemporal_load((const fvec4*)p);
}

// ---------------- kernel 1: support[b][n] = dot(X[b][n], w) ----------------
__global__ __launch_bounds__(256) void k_support(const float* __restrict__ X,
                                                 const float* __restrict__ W,
                                                 float* __restrict__ sup) {
    __shared__ float w_s[DFD];
    int t = threadIdx.x;
    if (t < DFD) w_s[t] = W[t];
    __syncthreads();
    int node = blockIdx.x * 64 + (t >> 2);   // global node in [0, B*N)
    int q = t & 3;                            // quarter of the D=128 row
    const float4* xp = (const float4*)(X + (size_t)node * DFD + q * 32);
    const float4* wp = (const float4*)(w_s + q * 32);
    float sum = 0.f;
#pragma unroll
    for (int i = 0; i < 8; ++i) {
        float4 x = xp[i], w = wp[i];
        sum += x.x * w.x + x.y * w.y + x.z * w.z + x.w * w.w;
    }
    sum += __shfl_xor(sum, 1);
    sum += __shfl_xor(sum, 2);
    if (q == 0) sup[node] = sum;
}

// --- kernel 2: attn = tanh(A·sup + b); ALSO emit packed binarized bitmask of A ---
// bm layout per row: 8 ulls indexed k = h*4+c (h = col>>8, c = col&3);
// bit position within ull = (col>>2)&63.
// 16 blocks/graph, 32 rows/block (8 per wave, processed in pipelined pairs).
__global__ __launch_bounds__(256) void k_score(const float* __restrict__ A,
                                               const float* __restrict__ sup,
                                               const float* __restrict__ bias,
                                               float* __restrict__ attn,
                                               ull* __restrict__ bm) {
    __shared__ float sup_s[NND];
    int b = blockIdx.x >> 4;
    int rblk = blockIdx.x & 15;
    int t = threadIdx.x;
    if (t < 128) ((float4*)sup_s)[t] = ((const float4*)(sup + (size_t)b * NND))[t];
    __syncthreads();
    int wave = t >> 6, l = t & 63;
    float bias0 = bias[0];
    const float4* sp = (const float4*)sup_s;
    float4 s0 = sp[l], s1 = sp[64 + l];
    int c0 = 4 * l;
    int row0 = rblk * 32 + wave * 8;
#pragma unroll 2
    for (int pr = 0; pr < 4; ++pr) {
        int rowA = row0 + pr * 2;
        int rowB = rowA + 1;
        const float* apA = A + ((size_t)b * NND + rowA) * NND;
        const float* apB = A + ((size_t)b * NND + rowB) * NND;
        fvec4 a0 = ntload4(apA + 4 * l),   a1 = ntload4(apA + 256 + 4 * l);
        fvec4 b0 = ntload4(apB + 4 * l),   b1 = ntload4(apB + 256 + 4 * l);
        float sA = a0.x * s0.x + a0.y * s0.y + a0.z * s0.z + a0.w * s0.w
                 + a1.x * s1.x + a1.y * s1.y + a1.z * s1.z + a1.w * s1.w;
        float sB = b0.x * s0.x + b0.y * s0.y + b0.z * s0.z + b0.w * s0.w
                 + b1.x * s1.x + b1.y * s1.y + b1.z * s1.z + b1.w * s1.w;
        ull mA[8], mB[8];
        mA[0] = __ballot(a0.x != 0.f && (c0 + 0) != rowA);
        mA[1] = __ballot(a0.y != 0.f && (c0 + 1) != rowA);
        mA[2] = __ballot(a0.z != 0.f && (c0 + 2) != rowA);
        mA[3] = __ballot(a0.w != 0.f && (c0 + 3) != rowA);
        mA[4] = __ballot(a1.x != 0.f && (256 + c0 + 0) != rowA);
        mA[5] = __ballot(a1.y != 0.f && (256 + c0 + 1) != rowA);
        mA[6] = __ballot(a1.z != 0.f && (256 + c0 + 2) != rowA);
        mA[7] = __ballot(a1.w != 0.f && (256 + c0 + 3) != rowA);
        mB[0] = __ballot(b0.x != 0.f && (c0 + 0) != rowB);
        mB[1] = __ballot(b0.y != 0.f && (c0 + 1) != rowB);
        mB[2] = __ballot(b0.z != 0.f && (c0 + 2) != rowB);
        mB[3] = __ballot(b0.w != 0.f && (c0 + 3) != rowB);
        mB[4] = __ballot(b1.x != 0.f && (256 + c0 + 0) != rowB);
        mB[5] = __ballot(b1.y != 0.f && (256 + c0 + 1) != rowB);
        mB[6] = __ballot(b1.z != 0.f && (256 + c0 + 2) != rowB);
        mB[7] = __ballot(b1.w != 0.f && (256 + c0 + 3) != rowB);
#pragma unroll
        for (int off = 32; off >= 1; off >>= 1) {
            sA += __shfl_xor(sA, off);
            sB += __shfl_xor(sB, off);
        }
        if (l == 0) {
            attn[b * NND + rowA] = tanhf(sA + bias0);
            attn[b * NND + rowB] = tanhf(sB + bias0);
            uint* bpA = (uint*)(bm + ((size_t)b * NND + rowA) * 8);
            uint* bpB = (uint*)(bm + ((size_t)b * NND + rowB) * 8);
#pragma unroll
            for (int k = 0; k < 4; ++k) {
                uvec4 wA = { (uint)mA[2*k], (uint)(mA[2*k] >> 32),
                             (uint)mA[2*k+1], (uint)(mA[2*k+1] >> 32) };
                uvec4 wB = { (uint)mB[2*k], (uint)(mB[2*k] >> 32),
                             (uint)mB[2*k+1], (uint)(mB[2*k+1] >> 32) };
                *((uvec4*)bpA + k) = wA;
                *((uvec4*)bpB + k) = wB;
            }
        }
    }
}

// --- kernel 3 (mega): 8 blocks/graph. Each block: rank/top-K (duplicated, LDS-only),
// bm gather -> K x K bits -> dinv (all LDS), then writes its eighth of
// hidden rows and adjacency rows (nontemporal). ---
__global__ __launch_bounds__(512) void k_mega(const float* __restrict__ X,
                                              const float* __restrict__ attn,
                                              const uint* __restrict__ bm,
                                              float* __restrict__ out_hidden,
                                              float* __restrict__ out_gi,
                                              float* __restrict__ out_adj) {
    __shared__ float attn_s[NND];
    __shared__ uint km[16];              // keep bitmask over 512 nodes
    __shared__ int idx_s[KKP];
    __shared__ uint4 bm_s4[KKP][4];      // gathered bitmask rows (16 uints each)
    __shared__ uint bits_s[KKP][8];      // K x K packed bits, K-order
    __shared__ float dinv_s[KKP];
    int b = blockIdx.x >> 3, q = blockIdx.x & 7;
    int t = threadIdx.x, wave = t >> 6, l = t & 63;
    attn_s[t] = attn[b * NND + t];
    __syncthreads();

    // rank of node t (strictly-greater, ties broken by smaller index)
    float a = attn_s[t];
    int r = 0;
    const float4* ap4 = (const float4*)attn_s;
    for (int jj = 0; jj < 128; ++jj) {
        float4 v = ap4[jj];
        int j0 = jj * 4;
        r += (v.x > a || (v.x == a && j0     < t)) ? 1 : 0;
        r += (v.y > a || (v.y == a && j0 + 1 < t)) ? 1 : 0;
        r += (v.z > a || (v.z == a && j0 + 2 < t)) ? 1 : 0;
        r += (v.w > a || (v.w == a && j0 + 3 < t)) ? 1 : 0;
    }
    bool keep = r < KKP;
    ull mk = __ballot(keep);
    if (l == 0) { km[wave * 2] = (uint)mk; km[wave * 2 + 1] = (uint)(mk >> 32); }
    __syncthreads();
    if (keep) {
        int w = t >> 5, pos = 0;
        for (int u = 0; u < w; ++u) pos += __popc(km[u]);
        pos += __popc(km[w] & ((1u << (t & 31)) - 1u));
        idx_s[pos] = t;
    }
    __syncthreads();

    // issue bm-row gather (latency hides under the hidden loop below)
    {
        int i = t >> 1, half = t & 1;
        const uint4* src = (const uint4*)(bm + ((size_t)b * NND + idx_s[i]) * 16) + half * 2;
        bm_s4[i][half * 2]     = src[0];
        bm_s4[i][half * 2 + 1] = src[1];
    }

    // hidden: this block's eighth (32 kept rows), one row per wave per iter
    if (q == 0 && t < KKP) out_gi[b * KKP + t] = (float)b;
#pragma unroll
    for (int it = 0; it < 4; ++it) {
        int k = q * 32 + it * 8 + wave;
        int node = idx_s[k];
        float s = attn_s[node];
        const float2* xp = (const float2*)(X + ((size_t)b * NND + node) * DFD);
        float2 v = xp[l];
        fvec2 v2 = { v.x * s, v.y * s };
        __builtin_nontemporal_store(v2, (fvec2*)(out_hidden + ((size_t)b * KKP + k) * DFD) + l);
    }
    __syncthreads();

    // assemble K x K bits: thread t handles kept-col j = t&255, rows ii+rowoff
    const uint* bmw = (const uint*)bm_s4;
    int jn = idx_s[t & 255];
    int widx = ((jn >> 8) * 4 + (jn & 3)) * 2 + ((jn >> 7) & 1);
    int bitpos = (jn >> 2) & 31;
    int rowoff = t >> 8;          // 0 or 1 (which half-block)
    int wq = (t >> 6) & 3;        // quarter of j-range this wave covers
    for (int ii = 0; ii < KKP; ii += 2) {
        int row = ii + rowoff;
        uint kb = (bmw[row * 16 + widx] >> bitpos) & 1u;
        ull mb = __ballot(kb != 0u);
        if (l == 0) {
            bits_s[row][wq * 2]     = (uint)mb;
            bits_s[row][wq * 2 + 1] = (uint)(mb >> 32);
        }
    }
    __syncthreads();
    if (t < KKP) {
        int s = 1;   // + I_K diagonal
#pragma unroll
        for (int k = 0; k < 8; ++k) s += __popc(bits_s[t][k]);
        dinv_s[t] = 1.0f / sqrtf((float)s);
    }
    __syncthreads();

    // adjacency: this block's eighth (32 rows), one row per wave per iter
    float4 dj = ((const float4*)dinv_s)[l];          // dinv for cols 4l..4l+3
    const float* djp = &dj.x;
#pragma unroll
    for (int it = 0; it < 4; ++it) {
        int i = q * 32 + it * 8 + wave;
        float di = dinv_s[i];
        uint word = bits_s[i][l >> 3];
        int j0 = l * 4;
        fvec4 v;
#pragma unroll
        for (int c = 0; c < 4; ++c) {
            int j = j0 + c;
            float ah = ((word >> (j & 31)) & 1u) ? 1.0f : 0.0f;
            if (j == i) ah += 1.0f;                  // + I_K
            v[c] = ah * di * djp[c];
        }
        __builtin_nontemporal_store(v, (fvec4*)(out_adj + ((size_t)b * KKP + i) * KKP) + l);
    }
}

extern "C" void kernel_launch(void* const* d_in, const int* in_sizes, int n_in,
                              void* d_out, int out_size, void* d_ws, size_t ws_size,
                              hipStream_t stream) {
    const float* A    = (const float*)d_in[0];   // [B,N,N]
    const float* X    = (const float*)d_in[1];   // [B,N,D]
    const float* W    = (const float*)d_in[3];   // [D,1]
    const float* bias = (const float*)d_in[4];   // [1]

    float* out        = (float*)d_out;
    float* out_hidden = out;                                     // B*K*D
    float* out_gi     = out + (size_t)BGR * KKP * DFD;           // B*K (as float)
    float* out_adj    = out_gi + (size_t)BGR * KKP;              // B*K*K

    float* sup  = (float*)d_ws;                                  // B*N
    float* attn = sup + (size_t)BGR * NND;                       // B*N
    ull*   bm   = (ull*)(attn + (size_t)BGR * NND);              // B*N*8 ulls (4MB)

    k_support<<<BGR * NND / 64, 256, 0, stream>>>(X, W, sup);
    k_score<<<BGR * 16, 256, 0, stream>>>(A, sup, bias, attn, bm);
    k_mega<<<BGR * 8, 512, 0, stream>>>(X, attn, (const uint*)bm,
                                        out_hidden, out_gi, out_adj);
}

// Round 7
// 70.844 us; speedup vs baseline: 1.2203x; 1.2203x over previous
//
#include <hip/hip_runtime.h>
#include <hip/hip_bf16.h>
#include <math.h>

#define BGR 128   // graphs
#define NND 512   // nodes per graph
#define DFD 128   // feature dim
#define KKP 256   // kept nodes per graph

typedef unsigned int uint;
typedef unsigned long long ull;

// ---------------- kernel 1: support[b][n] = dot(X[b][n], w) ----------------
__global__ __launch_bounds__(256) void k_support(const float* __restrict__ X,
                                                 const float* __restrict__ W,
                                                 float* __restrict__ sup) {
    __shared__ float w_s[DFD];
    int t = threadIdx.x;
    if (t < DFD) w_s[t] = W[t];
    __syncthreads();
    int node = blockIdx.x * 64 + (t >> 2);   // global node in [0, B*N)
    int q = t & 3;                            // quarter of the D=128 row
    const float4* xp = (const float4*)(X + (size_t)node * DFD + q * 32);
    const float4* wp = (const float4*)(w_s + q * 32);
    float sum = 0.f;
#pragma unroll
    for (int i = 0; i < 8; ++i) {
        float4 x = xp[i], w = wp[i];
        sum += x.x * w.x + x.y * w.y + x.z * w.z + x.w * w.w;
    }
    sum += __shfl_xor(sum, 1);
    sum += __shfl_xor(sum, 2);
    if (q == 0) sup[node] = sum;
}

// --- kernel 2: attn = tanh(A·sup + b); ALSO emit packed binarized bitmask of A ---
// bm layout per row: 8 ulls indexed k = h*4+c (h = col>>8, c = col&3);
// bit position within ull = (col>>2)&63.
__global__ __launch_bounds__(256) void k_score(const float* __restrict__ A,
                                               const float* __restrict__ sup,
                                               const float* __restrict__ bias,
                                               float* __restrict__ attn,
                                               ull* __restrict__ bm) {
    __shared__ float sup_s[NND];
    int b = blockIdx.x >> 6;       // 64 blocks per graph, 8 rows per block
    int rblk = blockIdx.x & 63;
    int t = threadIdx.x;
    sup_s[t] = sup[b * NND + t];
    sup_s[256 + t] = sup[b * NND + 256 + t];
    __syncthreads();
    int wave = t >> 6, l = t & 63;
    float bias0 = bias[0];
    const float4* sp = (const float4*)sup_s;
    float4 s0 = sp[l], s1 = sp[64 + l];
    int c0 = 4 * l;
#pragma unroll
    for (int r = 0; r < 2; ++r) {
        int row = rblk * 8 + wave * 2 + r;
        const float4* ap = (const float4*)(A + ((size_t)b * NND + row) * NND);
        float4 a0 = ap[l], a1 = ap[64 + l];
        float sum = a0.x * s0.x + a0.y * s0.y + a0.z * s0.z + a0.w * s0.w
                  + a1.x * s1.x + a1.y * s1.y + a1.z * s1.z + a1.w * s1.w;
        ull m[8];
        m[0] = __ballot(a0.x != 0.f && (c0 + 0) != row);
        m[1] = __ballot(a0.y != 0.f && (c0 + 1) != row);
        m[2] = __ballot(a0.z != 0.f && (c0 + 2) != row);
        m[3] = __ballot(a0.w != 0.f && (c0 + 3) != row);
        m[4] = __ballot(a1.x != 0.f && (256 + c0 + 0) != row);
        m[5] = __ballot(a1.y != 0.f && (256 + c0 + 1) != row);
        m[6] = __ballot(a1.z != 0.f && (256 + c0 + 2) != row);
        m[7] = __ballot(a1.w != 0.f && (256 + c0 + 3) != row);
#pragma unroll
        for (int off = 32; off >= 1; off >>= 1) sum += __shfl_xor(sum, off);
        // ballot results are wave-uniform: split the 64B row store across
        // lane 0 (first 32B) and lane 32 (last 32B), coalesced uint4 stores.
        uint4* bp = (uint4*)(bm + ((size_t)b * NND + row) * 8);
        if (l == 0) {
            attn[b * NND + row] = tanhf(sum + bias0);
            bp[0] = make_uint4((uint)m[0], (uint)(m[0] >> 32),
                               (uint)m[1], (uint)(m[1] >> 32));
            bp[1] = make_uint4((uint)m[2], (uint)(m[2] >> 32),
                               (uint)m[3], (uint)(m[3] >> 32));
        } else if (l == 32) {
            bp[2] = make_uint4((uint)m[4], (uint)(m[4] >> 32),
                               (uint)m[5], (uint)(m[5] >> 32));
            bp[3] = make_uint4((uint)m[6], (uint)(m[6] >> 32),
                               (uint)m[7], (uint)(m[7] >> 32));
        }
    }
}

// --- kernel 3 (mega): 4 blocks/graph. Each block: rank/top-K (duplicated, LDS-only),
// bm gather -> K x K bits -> dinv (all LDS), then writes its quarter of
// hidden rows and adjacency rows. No intermediate globals besides attn/bm.
__global__ __launch_bounds__(512) void k_mega(const float* __restrict__ X,
                                              const float* __restrict__ attn,
                                              const uint* __restrict__ bm,
                                              float* __restrict__ out_hidden,
                                              float* __restrict__ out_gi,
                                              float* __restrict__ out_adj) {
    __shared__ float attn_s[NND];
    __shared__ uint km[16];              // keep bitmask over 512 nodes
    __shared__ int idx_s[KKP];
    __shared__ uint4 bm_s4[KKP][4];      // gathered bitmask rows (16 uints each)
    __shared__ uint bits_s[KKP][8];      // K x K packed bits, K-order
    __shared__ float dinv_s[KKP];
    int b = blockIdx.x >> 2, q = blockIdx.x & 3;
    int t = threadIdx.x, wave = t >> 6, l = t & 63;
    attn_s[t] = attn[b * NND + t];
    __syncthreads();

    // rank of node t (strictly-greater, ties broken by smaller index)
    float a = attn_s[t];
    int r = 0;
    const float4* ap4 = (const float4*)attn_s;
    for (int jj = 0; jj < 128; ++jj) {
        float4 v = ap4[jj];
        int j0 = jj * 4;
        r += (v.x > a || (v.x == a && j0     < t)) ? 1 : 0;
        r += (v.y > a || (v.y == a && j0 + 1 < t)) ? 1 : 0;
        r += (v.z > a || (v.z == a && j0 + 2 < t)) ? 1 : 0;
        r += (v.w > a || (v.w == a && j0 + 3 < t)) ? 1 : 0;
    }
    bool keep = r < KKP;
    ull mk = __ballot(keep);
    if (l == 0) { km[wave * 2] = (uint)mk; km[wave * 2 + 1] = (uint)(mk >> 32); }
    __syncthreads();
    if (keep) {
        int w = t >> 5, pos = 0;
        for (int u = 0; u < w; ++u) pos += __popc(km[u]);
        pos += __popc(km[w] & ((1u << (t & 31)) - 1u));
        idx_s[pos] = t;
    }
    __syncthreads();

    // issue bm-row gather (latency hides under the hidden loop below)
    {
        int i = t >> 1, half = t & 1;
        const uint4* src = (const uint4*)(bm + ((size_t)b * NND + idx_s[i]) * 16) + half * 2;
        bm_s4[i][half * 2]     = src[0];
        bm_s4[i][half * 2 + 1] = src[1];
    }

    // hidden: this block's quarter (64 kept rows), one row per wave per iter
    if (q == 0 && t < KKP) out_gi[b * KKP + t] = (float)b;
#pragma unroll
    for (int it = 0; it < 8; ++it) {
        int k = q * 64 + it * 8 + wave;
        int node = idx_s[k];
        float s = attn_s[node];
        const float2* xp = (const float2*)(X + ((size_t)b * NND + node) * DFD);
        float2 v = xp[l];
        v.x *= s; v.y *= s;
        ((float2*)(out_hidden + ((size_t)b * KKP + k) * DFD))[l] = v;
    }
    __syncthreads();

    // assemble K x K bits: thread t handles kept-col j = t&255, rows ii+rowoff
    const uint* bmw = (const uint*)bm_s4;
    int jn = idx_s[t & 255];
    int widx = ((jn >> 8) * 4 + (jn & 3)) * 2 + ((jn >> 7) & 1);
    int bitpos = (jn >> 2) & 31;
    int rowoff = t >> 8;          // 0 or 1 (which half-block)
    int wq = (t >> 6) & 3;        // quarter of j-range this wave covers
    for (int ii = 0; ii < KKP; ii += 2) {
        int row = ii + rowoff;
        uint kb = (bmw[row * 16 + widx] >> bitpos) & 1u;
        ull mb = __ballot(kb != 0u);
        if (l == 0) {
            bits_s[row][wq * 2]     = (uint)mb;
            bits_s[row][wq * 2 + 1] = (uint)(mb >> 32);
        }
    }
    __syncthreads();
    if (t < KKP) {
        int s = 1;   // + I_K diagonal
#pragma unroll
        for (int k = 0; k < 8; ++k) s += __popc(bits_s[t][k]);
        dinv_s[t] = 1.0f / sqrtf((float)s);
    }
    __syncthreads();

    // adjacency: this block's quarter (64 rows), one row per wave per iter
    float4 dj = ((const float4*)dinv_s)[l];          // dinv for cols 4l..4l+3
    const float* djp = &dj.x;
#pragma unroll
    for (int it = 0; it < 8; ++it) {
        int i = q * 64 + it * 8 + wave;
        float di = dinv_s[i];
        uint word = bits_s[i][l >> 3];
        int j0 = l * 4;
        float4 v;
        float* pv = &v.x;
#pragma unroll
        for (int c = 0; c < 4; ++c) {
            int j = j0 + c;
            float ah = ((word >> (j & 31)) & 1u) ? 1.0f : 0.0f;
            if (j == i) ah += 1.0f;                  // + I_K
            pv[c] = ah * di * djp[c];
        }
        ((float4*)(out_adj + ((size_t)b * KKP + i) * KKP))[l] = v;
    }
}

extern "C" void kernel_launch(void* const* d_in, const int* in_sizes, int n_in,
                              void* d_out, int out_size, void* d_ws, size_t ws_size,
                              hipStream_t stream) {
    const float* A    = (const float*)d_in[0];   // [B,N,N]
    const float* X    = (const float*)d_in[1];   // [B,N,D]
    const float* W    = (const float*)d_in[3];   // [D,1]
    const float* bias = (const float*)d_in[4];   // [1]

    float* out        = (float*)d_out;
    float* out_hidden = out;                                     // B*K*D
    float* out_gi     = out + (size_t)BGR * KKP * DFD;           // B*K (as float)
    float* out_adj    = out_gi + (size_t)BGR * KKP;              // B*K*K

    float* sup  = (float*)d_ws;                                  // B*N
    float* attn = sup + (size_t)BGR * NND;                       // B*N
    ull*   bm   = (ull*)(attn + (size_t)BGR * NND);              // B*N*8 ulls (4MB)

    k_support<<<BGR * NND / 64, 256, 0, stream>>>(X, W, sup);
    k_score<<<BGR * 64, 256, 0, stream>>>(A, sup, bias, attn, bm);
    k_mega<<<BGR * 4, 512, 0, stream>>>(X, attn, (const uint*)bm,
                                        out_hidden, out_gi, out_adj);
}